// Round 1
// baseline (20119.148 us; speedup 1.0000x reference)
//
#include <hip/hip_runtime.h>
#include <hip/hip_cooperative_groups.h>

namespace cg = cooperative_groups;

#define NZzz 150
#define NXxx 300
#define NTT  1000
#define NSS  4
#define NRR  400
#define PW   (NXxx + 8)            // 308, padded width (4-cell zero halo each side)
#define PH   (NZzz + 8)            // 158
#define SHOT_STRIDE (PH * PW)      // 48664 floats per shot field

__global__ void wave_persistent(const float* __restrict__ v_map,
                                const float* __restrict__ s_amp,
                                const int*   __restrict__ s_loc,
                                const int*   __restrict__ r_loc,
                                float*       __restrict__ out,
                                float*       __restrict__ uA,
                                float*       __restrict__ uB) {
    cg::grid_group grid = cg::this_grid();

    const float DTf = 0.001f;
    const float inv_dx2 = 1.0f / (10.0f * 10.0f);
    const float c0 = -205.0f / 72.0f;
    const float c1 = 8.0f / 5.0f;
    const float c2 = -1.0f / 5.0f;
    const float c3 = 8.0f / 315.0f;
    const float c4 = -1.0f / 560.0f;

    const int z = blockIdx.x;    // 0..149
    const int x = threadIdx.x;   // 0..299
    const int idx = (z + 4) * PW + (x + 4);

    // v2dt2/dx^2 folded together (source scale must NOT include inv_dx2)
    float v2 = v_map[z * NXxx + x] * DTf;
    v2 = v2 * v2 * inv_dx2;

    int   src_idx[NSS];
    float src_scale[NSS];
#pragma unroll
    for (int s = 0; s < NSS; ++s) {
        const int szv = s_loc[2 * s];
        const int sxv = s_loc[2 * s + 1];
        src_idx[s] = (szv + 4) * PW + (sxv + 4);
        float sc = v_map[szv * NXxx + sxv] * DTf;
        src_scale[s] = sc * sc;
    }

    // receiver assignment: first NS*NR=1600 logical threads each own one (s,r)
    const int gtid = blockIdx.x * NXxx + threadIdx.x;
    int rec_s = -1, rec_r = 0, rec_idx = 0;
    if (gtid < NSS * NRR) {
        rec_s = gtid / NRR;
        rec_r = gtid - rec_s * NRR;
        const int rzv = r_loc[2 * rec_r];
        const int rxv = r_loc[2 * rec_r + 1];
        rec_idx = rec_s * SHOT_STRIDE + (rzv + 4) * PW + (rxv + 4);
    }

    for (int t = 0; t < NTT; ++t) {
        const float* cur = (t & 1) ? uB : uA;
        float*       prv = (t & 1) ? uA : uB;   // in-place: prv becomes u_next

#pragma unroll
        for (int s = 0; s < NSS; ++s) {
            const float* c = cur + s * SHOT_STRIDE;
            float*       p = prv + s * SHOT_STRIDE;
            const float uc = c[idx];
            float lap = 2.0f * c0 * uc;
            lap += c1 * (c[idx - 1] + c[idx + 1] + c[idx - PW] + c[idx + PW]);
            lap += c2 * (c[idx - 2] + c[idx + 2] + c[idx - 2 * PW] + c[idx + 2 * PW]);
            lap += c3 * (c[idx - 3] + c[idx + 3] + c[idx - 3 * PW] + c[idx + 3 * PW]);
            lap += c4 * (c[idx - 4] + c[idx + 4] + c[idx - 4 * PW] + c[idx + 4 * PW]);
            float un = 2.0f * uc - p[idx] + v2 * lap;
            if (idx == src_idx[s]) un += src_scale[s] * s_amp[s * NTT + t];
            p[idx] = un;
        }

        grid.sync();   // all u_next writes visible before neighbor reads / records

        if (rec_s >= 0) {
            out[(rec_s * NTT + t) * NRR + rec_r] = prv[rec_idx];
        }
        // next iter writes into the OTHER buffer (old cur), so records (reads of
        // prv) cannot race with t+1's writes; t+1's own sync re-serializes.
    }
}

extern "C" void kernel_launch(void* const* d_in, const int* in_sizes, int n_in,
                              void* d_out, int out_size, void* d_ws, size_t ws_size,
                              hipStream_t stream) {
    const float* v_map = (const float*)d_in[0];   // 150*300 f32
    const float* s_amp = (const float*)d_in[1];   // 4*1000 f32
    const int*   s_loc = (const int*)d_in[2];     // 4*2 i32
    const int*   r_loc = (const int*)d_in[3];     // 400*2 i32
    float* out = (float*)d_out;                   // 4*1000*400 f32

    float* uA = (float*)d_ws;
    float* uB = uA + NSS * SHOT_STRIDE;

    // zero both wavefields every call (deterministic; halo stays zero = BC)
    hipMemsetAsync(d_ws, 0, (size_t)(2 * NSS * SHOT_STRIDE) * sizeof(float), stream);

    void* args[] = { (void*)&v_map, (void*)&s_amp, (void*)&s_loc, (void*)&r_loc,
                     (void*)&out, (void*)&uA, (void*)&uB };
    hipLaunchCooperativeKernel((void*)wave_persistent,
                               dim3(NZzz), dim3(NXxx), args, 0, stream);
}

// Round 2
// 10901.712 us; speedup vs baseline: 1.8455x; 1.8455x over previous
//
#include <hip/hip_runtime.h>

// 2D acoustic FD propagator, 4 independent shots, NT=1000 sequential steps.
// Design: each shot split into NCH z-chunks; both wavefield buffers for a
// chunk live in LDS. Only halo rows (4 per side) are exchanged per step via
// agent-scope (MALL-coherent) atomics with a per-boundary flag handshake.
// No grid-wide barrier anywhere.

#define NZc 150
#define NXc 300
#define NTc 1000
#define NSc 4
#define NRc 400
#define CHc 15              // rows per chunk
#define NCHc 10             // chunks per shot  (CHc*NCHc == NZc)
#define LWc 308             // LDS row width: 4 + 300 + 4 zero pads
#define LRc (CHc + 8)       // 23 LDS rows: 4 halo + 15 interior + 4 halo
#define THR 160             // threads per block

typedef float f4 __attribute__((ext_vector_type(4)));

__device__ __forceinline__ float aload(float* p) {
    return __hip_atomic_load(p, __ATOMIC_RELAXED, __HIP_MEMORY_SCOPE_AGENT);
}
__device__ __forceinline__ void astore(float* p, float v) {
    __hip_atomic_store(p, v, __ATOMIC_RELAXED, __HIP_MEMORY_SCOPE_AGENT);
}
__device__ __forceinline__ float* hptr(float* halo, int s, int h, int dir, int par) {
    // halo[s][h][dir][par][4][300]
    return halo + (size_t)((((s * NCHc + h) * 2 + dir) * 2 + par) * 4) * 300;
}

// Compute NROWS output rows for one 4-wide column group. Vertical stencil from
// a sliding 9-row register window; horizontal from two extra b128 LDS reads.
template<int NROWS>
__device__ __forceinline__ void compute_band(const float (*cur)[LWc], float (*nxt)[LWc],
                                             const f4* v2r, int r0, int gc) {
    const float K0 = -205.0f / 72.0f, K1 = 8.0f / 5.0f, K2 = -1.0f / 5.0f,
                K3 = 8.0f / 315.0f,  K4 = -1.0f / 560.0f;
    f4 w[9];
#pragma unroll
    for (int i = 0; i < 8; ++i) w[i] = *(const f4*)&cur[r0 + i][gc];
#pragma unroll
    for (int i = 0; i < NROWS; ++i) {
        const int lr = r0 + i;                    // output local row; LDS row = 4+lr
        w[8] = *(const f4*)&cur[lr + 8][gc];
        const f4 lf = *(const f4*)&cur[lr + 4][gc - 4];
        const f4 rt = *(const f4*)&cur[lr + 4][gc + 4];
        const f4 pv = *(const f4*)&nxt[4 + lr][gc];   // u_prev (in-place)
        float xw[12];
#pragma unroll
        for (int j = 0; j < 4; ++j) { xw[j] = lf[j]; xw[4 + j] = w[4][j]; xw[8 + j] = rt[j]; }
        f4 res;
#pragma unroll
        for (int j = 0; j < 4; ++j) {
            const float ct = xw[4 + j];
            float lap = 2.0f * K0 * ct;
            lap += K1 * ((xw[j + 3] + xw[j + 5]) + (w[3][j] + w[5][j]));
            lap += K2 * ((xw[j + 2] + xw[j + 6]) + (w[2][j] + w[6][j]));
            lap += K3 * ((xw[j + 1] + xw[j + 7]) + (w[1][j] + w[7][j]));
            lap += K4 * ((xw[j + 0] + xw[j + 8]) + (w[0][j] + w[8][j]));
            res[j] = 2.0f * ct - pv[j] + v2r[i][j] * lap;
        }
        *(f4*)&nxt[4 + lr][gc] = res;
#pragma unroll
        for (int k = 0; k < 8; ++k) w[k] = w[k + 1];
    }
}

__global__ __launch_bounds__(THR) void wave_chunks(
    const float* __restrict__ v_map, const float* __restrict__ s_amp,
    const int* __restrict__ s_loc, const int* __restrict__ r_loc,
    float* __restrict__ out, int* flags, float* halo)
{
    const int bi = blockIdx.x;
    const int s = bi & 7;                 // shot = bi%8 -> all chunks of a shot
    const int h = bi >> 3;                // land on one XCD if round-robin holds
    if (s >= NSc) return;                 // (heuristic only; not needed for correctness)
    const int tid = threadIdx.x;
    const int z0 = h * CHc;

    __shared__ float buf[2][LRc][LWc];    // 56.7 KB, both halo'd (roles alternate)
    __shared__ short rzs[NRc], rxs[NRc];

    for (int i = tid; i < 2 * LRc * LWc; i += THR) ((float*)buf)[i] = 0.0f;
    for (int r = tid; r < NRc; r += THR) { rzs[r] = (short)r_loc[2 * r]; rxs[r] = (short)r_loc[2 * r + 1]; }

    // bands: tid<75 -> rows 0..7, 75<=tid<150 -> rows 8..14, rest idle in compute
    int g = 0, r0 = 0, nrows = 0;
    if (tid < 75)       { g = tid;       r0 = 0; nrows = 8; }
    else if (tid < 150) { g = tid - 75;  r0 = 8; nrows = 7; }
    const int gc = 4 + 4 * g;

    f4 v2r[8];
    if (nrows) {
#pragma unroll
        for (int i = 0; i < 8; ++i) {
            if (i < nrows) {
                f4 v = *(const f4*)&v_map[(z0 + r0 + i) * NXc + 4 * g];
                f4 t = v * 0.001f;                 // v*DT
                v2r[i] = t * t * 0.01f;            // (v*DT)^2 / DX^2
            }
        }
    }

    const int sz = s_loc[2 * s], sx = s_loc[2 * s + 1];
    float sscale = v_map[sz * NXc + sx] * 0.001f; sscale *= sscale;   // (v*DT)^2
    const int szl = sz - z0;
    const bool do_src = (tid == 0) && (szl >= 0) && (szl < CHc);
    // NOTE: injection row (sz=5) is interior and outside published boundary rows
    // (0..3, 11..14) and receiver row (rz=2); no intra-phase ordering needed.

    int* fUp = &flags[(s * NCHc + h) * 2 + 0];    // set by chunk h-1
    int* fDn = &flags[(s * NCHc + h) * 2 + 1];    // set by chunk h+1

    __syncthreads();

    for (int t = 0; t < NTc; ++t) {
        float (*cur)[LWc] = buf[t & 1];
        float (*nxt)[LWc] = buf[(t + 1) & 1];

        // ---- phase A: wait for neighbors' u(t) halos, ingest into cur ----
        if (t > 0) {
            const int par = (t - 1) & 1;
            if (tid < 80) {
                if (h > 0) {
                    while (__hip_atomic_load(fUp, __ATOMIC_RELAXED, __HIP_MEMORY_SCOPE_AGENT) < t) {}
                    float* src = hptr(halo, s, h, 0, par);
                    for (int e = tid; e < 1200; e += 80) {
                        const int row = e / 300, col = e - row * 300;
                        cur[row][4 + col] = aload(src + e);            // LDS rows 0..3
                    }
                }
            } else {
                if (h < NCHc - 1) {
                    while (__hip_atomic_load(fDn, __ATOMIC_RELAXED, __HIP_MEMORY_SCOPE_AGENT) < t) {}
                    float* src = hptr(halo, s, h, 1, par);
                    for (int e = tid - 80; e < 1200; e += 80) {
                        const int row = e / 300, col = e - row * 300;
                        cur[LRc - 4 + row][4 + col] = aload(src + e);  // LDS rows 19..22
                    }
                }
            }
        }
        __syncthreads();

        // ---- phase B: u_next = 2u - u_prev + v2dt2 * lap(u), in-place into nxt ----
        if (nrows == 8)      compute_band<8>(cur, nxt, v2r, 0, gc);
        else if (nrows == 7) compute_band<7>(cur, nxt, v2r, 8, gc);
        __syncthreads();

        // ---- phase C: inject source, record receivers, publish halos ----
        if (do_src) nxt[4 + szl][4 + sx] += sscale * s_amp[s * NTc + t];
        for (int r = tid; r < NRc; r += THR) {
            const int zr = (int)rzs[r] - z0;
            if (zr >= 0 && zr < CHc)
                out[((size_t)s * NTc + t) * NRc + r] = nxt[4 + zr][4 + (int)rxs[r]];
        }
        if (t < NTc - 1) {
            const int par = t & 1;
            for (int e = tid; e < 2400; e += THR) {
                if (e < 1200) {
                    if (h > 0) {                                  // top interior rows -> h-1
                        const int row = e / 300, col = e - row * 300;
                        astore(hptr(halo, s, h - 1, 1, par) + e, nxt[4 + row][4 + col]);
                    }
                } else {
                    if (h < NCHc - 1) {                           // bottom interior rows -> h+1
                        const int e2 = e - 1200;
                        const int row = e2 / 300, col = e2 - row * 300;
                        astore(hptr(halo, s, h + 1, 0, par) + e2, nxt[CHc + row][4 + col]);
                    }
                }
            }
        }
        asm volatile("s_waitcnt vmcnt(0)" ::: "memory");  // drain halo stores (release)
        __syncthreads();
        if (tid == 0 && t < NTc - 1) {
            if (h > 0)
                __hip_atomic_store(&flags[(s * NCHc + h - 1) * 2 + 1], t + 1,
                                   __ATOMIC_RELAXED, __HIP_MEMORY_SCOPE_AGENT);
            if (h < NCHc - 1)
                __hip_atomic_store(&flags[(s * NCHc + h + 1) * 2 + 0], t + 1,
                                   __ATOMIC_RELAXED, __HIP_MEMORY_SCOPE_AGENT);
        }
    }
}

extern "C" void kernel_launch(void* const* d_in, const int* in_sizes, int n_in,
                              void* d_out, int out_size, void* d_ws, size_t ws_size,
                              hipStream_t stream) {
    const float* v_map = (const float*)d_in[0];
    const float* s_amp = (const float*)d_in[1];
    const int*   s_loc = (const int*)d_in[2];
    const int*   r_loc = (const int*)d_in[3];
    float* out = (float*)d_out;

    int*   flags = (int*)d_ws;                         // 320 B used
    float* halo  = (float*)((char*)d_ws + 1024);       // 768 KB

    hipMemsetAsync(d_ws, 0, 1024, stream);             // reset flags each call

    wave_chunks<<<dim3(8 * (NCHc - 1) + NSc), dim3(THR), 0, stream>>>(
        v_map, s_amp, s_loc, r_loc, out, flags, halo);
}

// Round 3
// 3862.729 us; speedup vs baseline: 5.2085x; 2.8223x over previous
//
#include <hip/hip_runtime.h>

// 2D acoustic FD, 4 shots x 1000 steps. Temporal blocking K=4:
// chunk along X (full Z column resident in LDS, transposed layout),
// exchange 16-col halos of {u(t+4),u(t+3)} every 4 steps via agent-scope
// atomics + flag handshake. 18 chunks/shot x 4 shots = 72 blocks.

#define NZq 150
#define NXq 300
#define NTq 1000
#define NSq 4
#define NRq 400
#define KST 4
#define CHW 17              // interior cols per chunk
#define NCH 18              // chunks per shot (17*17=289, last chunk 11)
#define NBND (NCH-1)
#define ZW  164             // LDS row stride: 4 pad + 150 z + 4 pad + 6 align
#define LRr 49              // LDS rows: 16 halo + 17 interior + 16 halo
#define THRq 384
#define ZSTR 152
#define BUFFL (2*16*ZSTR)   // floats per (s,bnd,dir,par) strip
#define NRND (NTq/KST)      // 250

typedef float f4 __attribute__((ext_vector_type(4)));

__device__ __forceinline__ float aload(const float* p) {
    return __hip_atomic_load(p, __ATOMIC_RELAXED, __HIP_MEMORY_SCOPE_AGENT);
}
__device__ __forceinline__ void astore(float* p, float v) {
    __hip_atomic_store(p, v, __ATOMIC_RELAXED, __HIP_MEMORY_SCOPE_AGENT);
}

__global__ __launch_bounds__(THRq) void wave_tb(
    const float* __restrict__ v_map, const float* __restrict__ s_amp,
    const int* __restrict__ s_loc, const int* __restrict__ r_loc,
    float* __restrict__ out, int* __restrict__ flags, float* __restrict__ halo)
{
    const int bi = blockIdx.x;
    const int lo3 = bi & 7;
    const int s = lo3 & 3;                    // shot
    const int h = (bi >> 3) + 9 * (lo3 >> 2); // chunk 0..17; chain split over 2 XCDs (heuristic)
    const int tid = threadIdx.x;

    const int x0 = h * CHW;
    const int x1 = min(NXq, x0 + CHW);
    const int ch = x1 - x0;

    __shared__ float buf[2][LRr][ZW];         // 64,288 B; [row=x][col=4+z]
    for (int i = tid; i < 2*LRr*ZW; i += THRq) ((float*)buf)[i] = 0.0f;

    const int zg = tid % 38;                  // 4-wide z group
    const int xp = tid / 38;                  // x slice, 5 contiguous rows each
    const bool comp = (tid < 380);
    const int c0 = 4 + 4*zg;
    const int rbase = 5*xp;

    f4 v2r[5];                                // (v*DT)^2/DX^2 per owned row
#pragma unroll
    for (int i = 0; i < 5; ++i) {
        f4 vv = {0.f,0.f,0.f,0.f};
        const int row = rbase + i;
        const int x = x0 - 16 + row;
        if (comp && x >= 0 && x < NXq) {
#pragma unroll
            for (int j = 0; j < 4; ++j) {
                const int z = min(4*zg + j, NZq-1);
                const float v = v_map[z*NXq + x] * 0.001f;
                vv[j] = v*v*0.01f;
            }
        }
        v2r[i] = vv;
    }

    const int sz = s_loc[2*s], sx = s_loc[2*s+1];
    float sS = v_map[sz*NXq + sx] * 0.001f; sS = sS*sS;   // (v*DT)^2, no /dx^2
    const int srow = sx - x0 + 16;
    const int szg = sz >> 2;
    const int scol = 4 + sz;

    // receiver ownership (by interior), <=2 per thread
    int nrec = 0; int rI[2]; int rRow[2]; int rCol[2];
#pragma unroll
    for (int q = 0; q < 2; ++q) {
        const int rr = tid + q*THRq;
        if (rr < NRq) {
            const int rz = r_loc[2*rr];
            const int rx = r_loc[2*rr+1];
            if (rx >= x0 && rx < x1) { rI[nrec] = rr; rRow[nrec] = rx - x0 + 16; rCol[nrec] = 4 + rz; ++nrec; }
        }
    }

    __syncthreads();

    for (int r = 0; r < NRND; ++r) {
        for (int k = 1; k <= KST; ++k) {
            const int tau = 4*r + k;
            const int ext = 4*(KST - k);                       // 12,8,4,0
            const int L  = (h == 0) ? 16 : (16 - ext);
            const int Rr = 16 + ch + ((h == NCH-1) ? 0 : ext);
            const float (*cur)[ZW] = buf[(tau+1)&1];
            float (*nxt)[ZW] = buf[tau&1];                     // overwrites u(tau-2)

            if (comp) {
                f4 W[9];                                       // x-window rows row-4..row+4
#pragma unroll
                for (int q = 0; q < 8; ++q) {
                    int rr2 = rbase - 4 + q;
                    rr2 = max(0, min(LRr-1, rr2));
                    W[q] = *(const f4*)&cur[rr2][c0];
                }
#pragma unroll
                for (int i = 0; i < 5; ++i) {
                    const int row = rbase + i;
                    W[8] = *(const f4*)&cur[min(row+4, LRr-1)][c0];
                    if (row >= L && row < Rr) {
                        const f4 lf = *(const f4*)&cur[row][c0-4];
                        const f4 rt = *(const f4*)&cur[row][c0+4];
                        const f4 pv = *(const f4*)&nxt[row][c0];
                        float xw[12];
#pragma unroll
                        for (int j = 0; j < 4; ++j) { xw[j]=lf[j]; xw[4+j]=W[4][j]; xw[8+j]=rt[j]; }
                        f4 res;
#pragma unroll
                        for (int j = 0; j < 4; ++j) {
                            const float ct = xw[4+j];
                            float lap = 2.0f * (-205.0f/72.0f) * ct;
                            lap += (8.0f/5.0f)    * ((xw[j+3] + xw[j+5]) + (W[3][j] + W[5][j]));
                            lap += (-1.0f/5.0f)   * ((xw[j+2] + xw[j+6]) + (W[2][j] + W[6][j]));
                            lap += (8.0f/315.0f)  * ((xw[j+1] + xw[j+7]) + (W[1][j] + W[7][j]));
                            lap += (-1.0f/560.0f) * ((xw[j+0] + xw[j+8]) + (W[0][j] + W[8][j]));
                            res[j] = 2.0f*ct - pv[j] + v2r[i][j]*lap;
                        }
                        if (zg != 37) {
                            *(f4*)&nxt[row][c0] = res;
                        } else {                               // z=148,149 only; keep BC pads zero
                            nxt[row][c0]   = res[0];
                            nxt[row][c0+1] = res[1];
                        }
                        if (row == srow && zg == szg)          // region-based injection
                            nxt[row][scol] += sS * s_amp[s*NTq + tau - 1];
                    }
#pragma unroll
                    for (int q = 0; q < 8; ++q) W[q] = W[q+1];
                }
            }
            __syncthreads();
            const float (*nb)[ZW] = buf[tau&1];
            if (nrec > 0) out[((size_t)s*NTq + (tau-1))*NRq + rI[0]] = nb[rRow[0]][rCol[0]];
            if (nrec > 1) out[((size_t)s*NTq + (tau-1))*NRq + rI[1]] = nb[rRow[1]][rCol[1]];
        }

        if (r < NRND-1) {
            const int par = r & 1;
            // ---- publish: 16 interior edge cols of u(t+4)=buf[0], u(t+3)=buf[1] ----
            if (tid < 192) {
                if (h > 0) {                                   // left edge -> boundary(h-1), dir=1
                    const int nc = min(16, NXq - x0);
                    float* base = halo + (size_t)(((s*NBND + (h-1))*2 + 1)*2 + par) * BUFFL;
                    const int z = tid;
                    if (z < NZq)
                        for (int f = 0; f < 2; ++f)
                            for (int c = 0; c < nc; ++c)
                                astore(base + (f*16+c)*ZSTR + z, buf[f][16+c][4+z]);
                }
            } else {
                if (h < NCH-1) {                               // right edge -> boundary(h), dir=0
                    float* base = halo + (size_t)(((s*NBND + h)*2 + 0)*2 + par) * BUFFL;
                    const int z = tid - 192;
                    if (z < NZq)
                        for (int f = 0; f < 2; ++f)
                            for (int c = 0; c < 16; ++c)
                                astore(base + (f*16+c)*ZSTR + z, buf[f][ch+c][4+z]);
                }
            }
            asm volatile("s_waitcnt vmcnt(0)" ::: "memory");   // drain publishes (and records)
            __syncthreads();
            if (tid == 0) {
                if (h > 0)
                    __hip_atomic_store(&flags[(s*NBND + h-1)*2 + 1], r+1, __ATOMIC_RELAXED, __HIP_MEMORY_SCOPE_AGENT);
                if (h < NCH-1)
                    __hip_atomic_store(&flags[(s*NBND + h)*2 + 0], r+1, __ATOMIC_RELAXED, __HIP_MEMORY_SCOPE_AGENT);
            }
            if (tid == 0 && h > 0) {
                while (__hip_atomic_load(&flags[(s*NBND + h-1)*2 + 0], __ATOMIC_RELAXED, __HIP_MEMORY_SCOPE_AGENT) < r+1)
                    __builtin_amdgcn_s_sleep(1);
            }
            if (tid == 64 && h < NCH-1) {
                while (__hip_atomic_load(&flags[(s*NBND + h)*2 + 1], __ATOMIC_RELAXED, __HIP_MEMORY_SCOPE_AGENT) < r+1)
                    __builtin_amdgcn_s_sleep(1);
            }
            __syncthreads();
            // ---- ingest: refresh 16-col halos of BOTH buffers ----
            if (tid < 192) {
                if (h > 0) {
                    const float* base = halo + (size_t)(((s*NBND + (h-1))*2 + 0)*2 + par) * BUFFL;
                    const int z = tid;
                    if (z < NZq)
                        for (int f = 0; f < 2; ++f)
                            for (int c = 0; c < 16; ++c)
                                buf[f][c][4+z] = aload(base + (f*16+c)*ZSTR + z);
                }
            } else {
                if (h < NCH-1) {
                    const int nc = min(16, NXq - x1);
                    const float* base = halo + (size_t)(((s*NBND + h)*2 + 1)*2 + par) * BUFFL;
                    const int z = tid - 192;
                    if (z < NZq)
                        for (int f = 0; f < 2; ++f)
                            for (int c = 0; c < nc; ++c)
                                buf[f][16+ch+c][4+z] = aload(base + (f*16+c)*ZSTR + z);
                }
            }
            __syncthreads();
        }
    }
}

extern "C" void kernel_launch(void* const* d_in, const int* in_sizes, int n_in,
                              void* d_out, int out_size, void* d_ws, size_t ws_size,
                              hipStream_t stream) {
    const float* v_map = (const float*)d_in[0];
    const float* s_amp = (const float*)d_in[1];
    const int*   s_loc = (const int*)d_in[2];
    const int*   r_loc = (const int*)d_in[3];
    float* out = (float*)d_out;

    int*   flags = (int*)d_ws;                        // 544 B used
    float* halo  = (float*)((char*)d_ws + 1024);      // 272 * 4864 * 4 B = 5.05 MB

    hipMemsetAsync(d_ws, 0, 1024, stream);            // reset flags each call

    wave_tb<<<dim3(8*9), dim3(THRq), 0, stream>>>(v_map, s_amp, s_loc, r_loc, out, flags, halo);
}

// Round 4
// 3256.927 us; speedup vs baseline: 6.1773x; 1.1860x over previous
//
#include <hip/hip_runtime.h>

// 2D acoustic FD, 4 shots x 1000 steps. Temporal blocking K=8:
// 9 x-chunks/shot (33-34 interior cols), full z in LDS (transposed layout),
// 32-col halos of {u(t+8),u(t+7)} exchanged every 8 steps via agent-scope
// float2 atomics + distributed-poll flag handshake. 36 blocks, dynamic LDS.

#define NZ_ 150
#define NX_ 300
#define NT_ 1000
#define NS_ 4
#define NR_ 400
#define KS_ 8
#define NCH_ 9
#define NBND_ 8
#define HW_ 32               // halo width = 4*KS
#define ZW_ 168              // LDS z-stride (4 pad + 150 + 4 pad + align)
#define LROWS_ 98            // 32 + 34 + 32 max rows per chunk
#define THR_ 512
#define NRND_ 125
#define HELEMS_ 4800         // float2 per (s,bnd,dir,par): 2 fields*32 rows*75 zpairs

typedef float f4 __attribute__((ext_vector_type(4)));
typedef unsigned long long u64;

__device__ __forceinline__ u64 aload64(const u64* p) {
    return __hip_atomic_load(p, __ATOMIC_RELAXED, __HIP_MEMORY_SCOPE_AGENT);
}
__device__ __forceinline__ void astore64(u64* p, u64 v) {
    __hip_atomic_store(p, v, __ATOMIC_RELAXED, __HIP_MEMORY_SCOPE_AGENT);
}
__device__ __forceinline__ int aload32(const int* p) {
    return __hip_atomic_load(p, __ATOMIC_RELAXED, __HIP_MEMORY_SCOPE_AGENT);
}
__device__ __forceinline__ void astore32(int* p, int v) {
    __hip_atomic_store(p, v, __ATOMIC_RELAXED, __HIP_MEMORY_SCOPE_AGENT);
}

__global__ __launch_bounds__(THR_) void wave_tb8(
    const float* __restrict__ v_map, const float* __restrict__ s_amp,
    const int* __restrict__ s_loc, const int* __restrict__ r_loc,
    float* __restrict__ out, int* __restrict__ flags, u64* __restrict__ halo)
{
    extern __shared__ float smem[];
    const int bi = blockIdx.x;
    const int s = bi & 3;
    const int h = bi >> 2;                       // 0..8
    const int tid = threadIdx.x;

    const int w  = 33 + (h < 3 ? 1 : 0);         // interior cols (>= HW_ required? no: >=32 ok)
    const int x0 = 33 * h + (h < 3 ? h : 3);
    const int rows_hi = HW_ + w;                 // end of interior rows

    for (int i = tid; i < 2 * LROWS_ * ZW_; i += THR_) smem[i] = 0.0f;

    const int zg = tid % 38;                     // 4-wide z group, cols c0..c0+3
    const int xp = tid / 38;                     // x-slice, 8 rows each
    const bool comp = (tid < 494);               // 38*13
    const int c0 = 4 + 4 * zg;
    const int rbase = 8 * xp;

    f4 v2r[8];
#pragma unroll
    for (int i = 0; i < 8; ++i) {
        f4 vv = {0.f, 0.f, 0.f, 0.f};
        const int row = rbase + i;
        const int x = x0 - HW_ + row;
        if (comp && x >= 0 && x < NX_) {
#pragma unroll
            for (int j = 0; j < 4; ++j) {
                const int z = min(4 * zg + j, NZ_ - 1);
                const float v = v_map[z * NX_ + x] * 0.001f;
                vv[j] = v * v * 0.01f;           // (v*DT)^2 / DX^2
            }
        }
        v2r[i] = vv;
    }

    const int sz = s_loc[2 * s], sx = s_loc[2 * s + 1];
    float sS = v_map[sz * NX_ + sx] * 0.001f; sS = sS * sS;   // (v*DT)^2
    const int srow = sx - x0 + HW_;
    const int szg = sz >> 2;
    const int scol = 4 + sz;

    // receiver ownership: thread tid owns receiver tid (NR_ <= THR_)
    bool rown = false; int rrow = 0, rcol = 0;
    if (tid < NR_) {
        const int rz = r_loc[2 * tid];
        const int rx = r_loc[2 * tid + 1];
        if (rx >= x0 && rx < x0 + w) { rown = true; rrow = HW_ + rx - x0; rcol = 4 + rz; }
    }

    __syncthreads();

    for (int r = 0; r < NRND_; ++r) {
        for (int k = 1; k <= KS_; ++k) {
            const int tau = KS_ * r + k;
            const int ext = 4 * (KS_ - k);                     // 28..0
            const int L  = (h == 0)        ? HW_     : HW_ - ext;
            const int R  = (h == NCH_ - 1) ? rows_hi : rows_hi + ext;
            const float* cur = smem + ((tau + 1) & 1) * (LROWS_ * ZW_);
            float*       nxt = smem + (tau & 1)       * (LROWS_ * ZW_);

            if (comp && rbase < R && rbase + 8 > L) {
                f4 W[9];
#pragma unroll
                for (int q = 0; q < 8; ++q) {
                    int rr = rbase - 4 + q; rr = rr < 0 ? 0 : rr;
                    W[q] = *(const f4*)&cur[rr * ZW_ + c0];
                }
#pragma unroll
                for (int i = 0; i < 8; ++i) {
                    const int row = rbase + i;
                    const int wr = (row + 4 < LROWS_) ? (row + 4) : (LROWS_ - 1);
                    W[8] = *(const f4*)&cur[wr * ZW_ + c0];
                    if (row >= L && row < R) {
                        const f4 lf = *(const f4*)&cur[row * ZW_ + c0 - 4];
                        const f4 rt = *(const f4*)&cur[row * ZW_ + c0 + 4];
                        const f4 pv = *(const f4*)&nxt[row * ZW_ + c0];
                        float xw[12];
#pragma unroll
                        for (int j = 0; j < 4; ++j) { xw[j] = lf[j]; xw[4 + j] = W[4][j]; xw[8 + j] = rt[j]; }
                        f4 res;
#pragma unroll
                        for (int j = 0; j < 4; ++j) {
                            const float ct = xw[4 + j];
                            float lap = 2.0f * (-205.0f / 72.0f) * ct;
                            lap += (8.0f / 5.0f)    * ((xw[j + 3] + xw[j + 5]) + (W[3][j] + W[5][j]));
                            lap += (-1.0f / 5.0f)   * ((xw[j + 2] + xw[j + 6]) + (W[2][j] + W[6][j]));
                            lap += (8.0f / 315.0f)  * ((xw[j + 1] + xw[j + 7]) + (W[1][j] + W[7][j]));
                            lap += (-1.0f / 560.0f) * ((xw[j + 0] + xw[j + 8]) + (W[0][j] + W[8][j]));
                            res[j] = 2.0f * ct - pv[j] + v2r[i][j] * lap;
                        }
                        if (zg != 37) {
                            *(f4*)&nxt[row * ZW_ + c0] = res;
                        } else {                               // z=148,149 only; keep pads zero
                            nxt[row * ZW_ + c0]     = res[0];
                            nxt[row * ZW_ + c0 + 1] = res[1];
                        }
                        if (row == srow && zg == szg)
                            nxt[row * ZW_ + scol] += sS * s_amp[s * NT_ + tau - 1];
                    }
#pragma unroll
                    for (int q = 0; q < 8; ++q) W[q] = W[q + 1];
                }
            }
            __syncthreads();
            if (rown) {
                const float* nb = smem + (tau & 1) * (LROWS_ * ZW_);
                out[((size_t)s * NT_ + (tau - 1)) * NR_ + tid] = nb[rrow * ZW_ + rcol];
            }
        }

        if (r < NRND_ - 1) {
            const int par = r & 1;
            // ---- publish 32 interior edge cols of u(t+8)=buf0, u(t+7)=buf1 ----
            if (tid < 256) {
                if (h > 0) {
                    u64* dst = halo + (size_t)(((s * NBND_ + h - 1) * 2 + 1) * 2 + par) * HELEMS_;
                    for (int e = tid; e < HELEMS_; e += 256) {
                        const int f = e / 2400;
                        const int rem = e - f * 2400;
                        const int row = rem / 75;
                        const int zp = rem - row * 75;
                        u64 v = *(const u64*)&smem[f * (LROWS_ * ZW_) + (HW_ + row) * ZW_ + 4 + 2 * zp];
                        astore64(dst + e, v);
                    }
                }
            } else {
                if (h < NCH_ - 1) {
                    u64* dst = halo + (size_t)(((s * NBND_ + h) * 2 + 0) * 2 + par) * HELEMS_;
                    for (int e = tid - 256; e < HELEMS_; e += 256) {
                        const int f = e / 2400;
                        const int rem = e - f * 2400;
                        const int row = rem / 75;
                        const int zp = rem - row * 75;
                        u64 v = *(const u64*)&smem[f * (LROWS_ * ZW_) + (w + row) * ZW_ + 4 + 2 * zp];
                        astore64(dst + e, v);
                    }
                }
            }
            asm volatile("s_waitcnt vmcnt(0)" ::: "memory");   // drain own publishes
            __syncthreads();                                    // all blocks' stores drained
            if (tid == 0) {
                if (h > 0)
                    astore32(&flags[(s * NBND_ + h - 1) * 2 + 1], r + 1);
                if (h < NCH_ - 1)
                    astore32(&flags[(s * NBND_ + h) * 2 + 0], r + 1);
            }
            // ---- distributed poll + ingest (both buffers' halo rows) ----
            if (tid < 256) {
                if (h > 0) {
                    const int* fp = &flags[(s * NBND_ + h - 1) * 2 + 0];
                    while (aload32(fp) <= r) __builtin_amdgcn_s_sleep(2);
                    const u64* src = halo + (size_t)(((s * NBND_ + h - 1) * 2 + 0) * 2 + par) * HELEMS_;
                    for (int e = tid; e < HELEMS_; e += 256) {
                        const int f = e / 2400;
                        const int rem = e - f * 2400;
                        const int row = rem / 75;
                        const int zp = rem - row * 75;
                        *(u64*)&smem[f * (LROWS_ * ZW_) + row * ZW_ + 4 + 2 * zp] = aload64(src + e);
                    }
                }
            } else {
                if (h < NCH_ - 1) {
                    const int* fp = &flags[(s * NBND_ + h) * 2 + 1];
                    while (aload32(fp) <= r) __builtin_amdgcn_s_sleep(2);
                    const u64* src = halo + (size_t)(((s * NBND_ + h) * 2 + 1) * 2 + par) * HELEMS_;
                    for (int e = tid - 256; e < HELEMS_; e += 256) {
                        const int f = e / 2400;
                        const int rem = e - f * 2400;
                        const int row = rem / 75;
                        const int zp = rem - row * 75;
                        *(u64*)&smem[f * (LROWS_ * ZW_) + (rows_hi + row) * ZW_ + 4 + 2 * zp] = aload64(src + e);
                    }
                }
            }
            __syncthreads();
        }
    }
}

extern "C" void kernel_launch(void* const* d_in, const int* in_sizes, int n_in,
                              void* d_out, int out_size, void* d_ws, size_t ws_size,
                              hipStream_t stream) {
    const float* v_map = (const float*)d_in[0];
    const float* s_amp = (const float*)d_in[1];
    const int*   s_loc = (const int*)d_in[2];
    const int*   r_loc = (const int*)d_in[3];
    float* out = (float*)d_out;

    int* flags = (int*)d_ws;                        // 64 ints
    u64* halo  = (u64*)((char*)d_ws + 1024);        // 4*8*2*2*4800*8 = 4.92 MB

    hipMemsetAsync(d_ws, 0, 1024, stream);          // reset flags each call

    const int smem_bytes = 2 * LROWS_ * ZW_ * 4;    // 131,712 B
    static bool attr_set = false;
    if (!attr_set) {                                // idempotent, host-side only
        hipFuncSetAttribute((const void*)wave_tb8,
                            hipFuncAttributeMaxDynamicSharedMemorySize, smem_bytes);
        attr_set = true;
    }

    wave_tb8<<<dim3(NS_ * NCH_), dim3(THR_), smem_bytes, stream>>>(
        v_map, s_amp, s_loc, r_loc, out, flags, halo);
}

// Round 6
// 2825.822 us; speedup vs baseline: 7.1198x; 1.1526x over previous
//
#include <hip/hip_runtime.h>

// 2D acoustic FD, 4 shots x 1000 steps. Temporal blocking K=8:
// 9 x-chunks/shot (33-34 interior cols), full z in LDS (transposed layout),
// 32-col halos of {u(t+8),u(t+7)} exchanged every 8 steps via agent-scope
// protocol. R6: ingest uses BATCHED issue (19 global_load_dwordx2 sc0 sc1 in
// flight, ONE vmcnt wait) instead of 19 serialized load->use round trips.

#define NZ_ 150
#define NX_ 300
#define NT_ 1000
#define NS_ 4
#define NR_ 400
#define KS_ 8
#define NCH_ 9
#define NBND_ 8
#define HW_ 32               // halo width = 4*KS
#define ZW_ 168              // LDS z-stride (4 pad + 150 + 4 pad + align)
#define LROWS_ 98            // 32 + 34 + 32 max rows per chunk
#define BUF_ (LROWS_*ZW_)
#define THR_ 512
#define NRND_ 125
#define HELE_ 4800           // u64 per (s,bnd,dir,par): 2 fields*32 rows*75 zpairs
#define NBATCH 19            // ceil(4800/256)

typedef float f4 __attribute__((ext_vector_type(4)));
typedef unsigned long long u64;

__device__ __forceinline__ void astore64(u64* p, u64 v) {
    __hip_atomic_store(p, v, __ATOMIC_RELAXED, __HIP_MEMORY_SCOPE_AGENT);
}
__device__ __forceinline__ int aload32(const int* p) {
    return __hip_atomic_load(p, __ATOMIC_RELAXED, __HIP_MEMORY_SCOPE_AGENT);
}
__device__ __forceinline__ void astore32(int* p, int v) {
    __hip_atomic_store(p, v, __ATOMIC_RELAXED, __HIP_MEMORY_SCOPE_AGENT);
}
// batched ingest: issue without waiting; sc0 sc1 = bypass L1+L2, read MALL
__device__ __forceinline__ void ld2_issue(u64& d, const u64* p) {
    asm volatile("global_load_dwordx2 %0, %1, off sc0 sc1" : "=v"(d) : "v"(p));
}

__global__ __launch_bounds__(THR_) void wave_tb8b(
    const float* __restrict__ v_map, const float* __restrict__ s_amp,
    const int* __restrict__ s_loc, const int* __restrict__ r_loc,
    float* __restrict__ out, int* __restrict__ flags, u64* __restrict__ halo)
{
    extern __shared__ float smem[];
    const int bi = blockIdx.x;
    const int s = bi & 3;
    const int h = bi >> 2;                       // 0..8
    const int tid = threadIdx.x;

    const int w  = 33 + (h < 3 ? 1 : 0);
    const int x0 = 33 * h + (h < 3 ? h : 3);
    const int rhi = HW_ + w;

    for (int i = tid; i < 2 * BUF_; i += THR_) smem[i] = 0.0f;

    const int zg = tid % 38;                     // 4-wide z group
    const int xp = tid / 38;                     // x-slice, 8 rows each
    const bool comp = (tid < 494);               // 38*13
    const int c0 = 4 + 4 * zg;
    const int rbase = 8 * xp;

    f4 v2r[8];
#pragma unroll
    for (int i = 0; i < 8; ++i) {
        f4 vv = {0.f, 0.f, 0.f, 0.f};
        const int row = rbase + i;
        const int x = x0 - HW_ + row;
        if (comp && x >= 0 && x < NX_) {
#pragma unroll
            for (int j = 0; j < 4; ++j) {
                const int z = min(4 * zg + j, NZ_ - 1);
                const float v = v_map[z * NX_ + x] * 0.001f;
                vv[j] = v * v * 0.01f;           // (v*DT)^2 / DX^2
            }
        }
        v2r[i] = vv;
    }

    const int sz = s_loc[2 * s], sx = s_loc[2 * s + 1];
    float sS = v_map[sz * NX_ + sx] * 0.001f; sS = sS * sS;   // (v*DT)^2
    const int srow = sx - x0 + HW_;
    const int szg = sz >> 2;
    const int scol = 4 + sz;

    bool rown = false; int rrow = 0, rcol = 0;
    if (tid < NR_) {
        const int rz = r_loc[2 * tid];
        const int rx = r_loc[2 * tid + 1];
        if (rx >= x0 && rx < x0 + w) { rown = true; rrow = HW_ + rx - x0; rcol = 4 + rz; }
    }

    __syncthreads();

    for (int r = 0; r < NRND_; ++r) {
        for (int k = 1; k <= KS_; ++k) {
            const int tau = KS_ * r + k;
            const int ext = 4 * (KS_ - k);                     // 28..0
            const int L  = (h == 0)        ? HW_ : HW_ - ext;
            const int R  = (h == NCH_ - 1) ? rhi : rhi + ext;
            const float* cur = smem + ((tau + 1) & 1) * BUF_;
            float*       nxt = smem + (tau & 1) * BUF_;

            if (comp && rbase < R && rbase + 8 > L) {
                f4 W[9];
#pragma unroll
                for (int q = 0; q < 8; ++q) {
                    int rr = rbase - 4 + q; rr = rr < 0 ? 0 : rr;
                    W[q] = *(const f4*)&cur[rr * ZW_ + c0];
                }
#pragma unroll
                for (int i = 0; i < 8; ++i) {
                    const int row = rbase + i;
                    const int wr = (row + 4 < LROWS_) ? (row + 4) : (LROWS_ - 1);
                    W[8] = *(const f4*)&cur[wr * ZW_ + c0];
                    if (row >= L && row < R) {
                        const f4 lf = *(const f4*)&cur[row * ZW_ + c0 - 4];
                        const f4 rt = *(const f4*)&cur[row * ZW_ + c0 + 4];
                        const f4 pv = *(const f4*)&nxt[row * ZW_ + c0];
                        float xw[12];
#pragma unroll
                        for (int j = 0; j < 4; ++j) { xw[j] = lf[j]; xw[4 + j] = W[4][j]; xw[8 + j] = rt[j]; }
                        f4 res;
#pragma unroll
                        for (int j = 0; j < 4; ++j) {
                            const float ct = xw[4 + j];
                            float lap = 2.0f * (-205.0f / 72.0f) * ct;
                            lap += (8.0f / 5.0f)    * ((xw[j + 3] + xw[j + 5]) + (W[3][j] + W[5][j]));
                            lap += (-1.0f / 5.0f)   * ((xw[j + 2] + xw[j + 6]) + (W[2][j] + W[6][j]));
                            lap += (8.0f / 315.0f)  * ((xw[j + 1] + xw[j + 7]) + (W[1][j] + W[7][j]));
                            lap += (-1.0f / 560.0f) * ((xw[j + 0] + xw[j + 8]) + (W[0][j] + W[8][j]));
                            res[j] = 2.0f * ct - pv[j] + v2r[i][j] * lap;
                        }
                        if (zg != 37) {
                            *(f4*)&nxt[row * ZW_ + c0] = res;
                        } else {                               // z=148,149; keep pads zero
                            nxt[row * ZW_ + c0]     = res[0];
                            nxt[row * ZW_ + c0 + 1] = res[1];
                        }
                        if (row == srow && zg == szg)
                            nxt[row * ZW_ + scol] += sS * s_amp[s * NT_ + tau - 1];
                    }
#pragma unroll
                    for (int q = 0; q < 8; ++q) W[q] = W[q + 1];
                }
            }
            __syncthreads();
            if (rown) {
                const float* nb = smem + (tau & 1) * BUF_;
                out[((size_t)s * NT_ + (tau - 1)) * NR_ + tid] = nb[rrow * ZW_ + rcol];
            }
        }

        if (r < NRND_ - 1) {
            const int par = r & 1;
            // ---- publish 32 interior edge cols of u(t+8)=buf0, u(t+7)=buf1 ----
            if (tid < 256) {
                if (h > 0) {
                    u64* dst = halo + (size_t)(((s * NBND_ + h - 1) * 2 + 1) * 2 + par) * HELE_;
                    for (int e = tid; e < HELE_; e += 256) {
                        const int f = e / 2400, rem = e - f * 2400, row = rem / 75, zp = rem - row * 75;
                        astore64(dst + e, *(const u64*)&smem[f * BUF_ + (HW_ + row) * ZW_ + 4 + 2 * zp]);
                    }
                }
            } else {
                if (h < NCH_ - 1) {
                    u64* dst = halo + (size_t)(((s * NBND_ + h) * 2 + 0) * 2 + par) * HELE_;
                    for (int e = tid - 256; e < HELE_; e += 256) {
                        const int f = e / 2400, rem = e - f * 2400, row = rem / 75, zp = rem - row * 75;
                        astore64(dst + e, *(const u64*)&smem[f * BUF_ + (w + row) * ZW_ + 4 + 2 * zp]);
                    }
                }
            }
            asm volatile("s_waitcnt vmcnt(0)" ::: "memory");   // drain own publishes
            __syncthreads();
            if (tid == 0) {
                if (h > 0)
                    astore32(&flags[(s * NBND_ + h - 1) * 2 + 1], r + 1);
                if (h < NCH_ - 1)
                    astore32(&flags[(s * NBND_ + h) * 2 + 0], r + 1);
            }
            // ---- distributed poll, then BATCHED ingest (1 wait, not 19) ----
            if (tid < 256) {
                if (h > 0) {
                    const int* fp = &flags[(s * NBND_ + h - 1) * 2 + 0];
                    while (aload32(fp) <= r) __builtin_amdgcn_s_sleep(1);
                    const u64* src = halo + (size_t)(((s * NBND_ + h - 1) * 2 + 0) * 2 + par) * HELE_;
                    u64 vb[NBATCH];
#pragma unroll
                    for (int q = 0; q < NBATCH; ++q) {
                        const int e = tid + 256 * q;
                        ld2_issue(vb[q], src + (e < HELE_ ? e : HELE_ - 1));
                    }
                    asm volatile("s_waitcnt vmcnt(0)" ::: "memory");
                    __builtin_amdgcn_sched_barrier(0);
#pragma unroll
                    for (int q = 0; q < NBATCH; ++q) {
                        const int e = tid + 256 * q;
                        if (e < HELE_) {
                            const int f = e / 2400, rem = e - f * 2400, row = rem / 75, zp = rem - row * 75;
                            *(u64*)&smem[f * BUF_ + row * ZW_ + 4 + 2 * zp] = vb[q];
                        }
                    }
                }
            } else {
                if (h < NCH_ - 1) {
                    const int* fp = &flags[(s * NBND_ + h) * 2 + 1];
                    while (aload32(fp) <= r) __builtin_amdgcn_s_sleep(1);
                    const u64* src = halo + (size_t)(((s * NBND_ + h) * 2 + 1) * 2 + par) * HELE_;
                    u64 vb[NBATCH];
#pragma unroll
                    for (int q = 0; q < NBATCH; ++q) {
                        const int e = (tid - 256) + 256 * q;
                        ld2_issue(vb[q], src + (e < HELE_ ? e : HELE_ - 1));
                    }
                    asm volatile("s_waitcnt vmcnt(0)" ::: "memory");
                    __builtin_amdgcn_sched_barrier(0);
#pragma unroll
                    for (int q = 0; q < NBATCH; ++q) {
                        const int e = (tid - 256) + 256 * q;
                        if (e < HELE_) {
                            const int f = e / 2400, rem = e - f * 2400, row = rem / 75, zp = rem - row * 75;
                            *(u64*)&smem[f * BUF_ + (rhi + row) * ZW_ + 4 + 2 * zp] = vb[q];
                        }
                    }
                }
            }
            __syncthreads();
        }
    }
}

extern "C" void kernel_launch(void* const* d_in, const int* in_sizes, int n_in,
                              void* d_out, int out_size, void* d_ws, size_t ws_size,
                              hipStream_t stream) {
    const float* v_map = (const float*)d_in[0];
    const float* s_amp = (const float*)d_in[1];
    const int*   s_loc = (const int*)d_in[2];
    const int*   r_loc = (const int*)d_in[3];
    float* out = (float*)d_out;

    int* flags = (int*)d_ws;                        // 64 ints
    u64* halo  = (u64*)((char*)d_ws + 1024);        // 4*8*2*2*4800*8 = 4.92 MB

    hipMemsetAsync(d_ws, 0, 1024, stream);          // reset flags each call

    const int smem_bytes = 2 * BUF_ * 4;            // 131,712 B
    static bool attr_set = false;
    if (!attr_set) {                                // host-side, idempotent
        hipFuncSetAttribute((const void*)wave_tb8b,
                            hipFuncAttributeMaxDynamicSharedMemorySize, smem_bytes);
        attr_set = true;
    }

    wave_tb8b<<<dim3(NS_ * NCH_), dim3(THR_), smem_bytes, stream>>>(
        v_map, s_amp, s_loc, r_loc, out, flags, halo);
}